// Round 4
// baseline (7004.485 us; speedup 1.0000x reference)
//
#include <hip/hip_runtime.h>
#include <hip/hip_bf16.h>

// ---------------------------------------------------------------------------
// 2-layer tanh RNN + FC head on MI355X (gfx950).
// Round 7: round-6 structure (verified XCD-local groups, FETCH 794->141MB)
// with the two critical-path fixes:
//   (a) weights pinned in AGPRs ("+a") -- round 6 pinned 256 VGPRs/lane in
//       the L1 branch against a 160-VGPR allocation => per-step spill reload
//       on the serial chain (the 2670->4845us regression).
//   (b) flag handshake at XCD-L2 scope (sc0) when local, with dual-publish
//       (separate 256B-padded agent lines) + bounded sticky fallback =>
//       no deadlock channel if sc0 semantics differ.
//   B=64 S=512 I=256 H=1024 O=256
//   grid 256: bx%8 even -> group (bx%8)/2, rank bx/8 (0..31):
//     rank<16 : layer-0 WG, 64 cols;  rank>=16: layer-1 WG, 64 cols
//   bx%8 odd -> exit (latency-bound chain; extra CUs can't help)
// ---------------------------------------------------------------------------

typedef __attribute__((ext_vector_type(4))) float f32x4;
typedef __attribute__((ext_vector_type(8))) short bf16x8;
typedef __attribute__((ext_vector_type(4))) int   i32x4;
typedef __attribute__((ext_vector_type(4))) short s16x4;

#define B_  64
#define S_  512
#define I_  256
#define H_  1024
#define O_  256
#define M_  (B_ * S_)     // 32768
#define SH_ (S_ * H_)     // 524288 (row stride of h-seq / pre in elements)
#define NACT 128          // active WGs (4 groups x 32)
#define POISON_TAG 0xFFu  // nonzero, != any real tag (tags are 1..16)

static __device__ __forceinline__ unsigned short f2bf(float f) {
  union { float f; unsigned u; } v; v.f = f;
  unsigned r = v.u + 0x7fffu + ((v.u >> 16) & 1u);   // RNE
  return (unsigned short)(r >> 16);
}
static __device__ __forceinline__ float bf2f(unsigned short b) {
  union { unsigned u; float f; } v; v.u = ((unsigned)b) << 16;
  return v.f;
}
static __device__ __forceinline__ float tanh_fast(float x) {
  float e = __expf(2.f * x);
  return 1.f - 2.f / (e + 1.f);
}
static __device__ __forceinline__ bf16x8 as_bf16x8(i32x4 v) {
  union { i32x4 i; bf16x8 b; } u; u.i = v; return u.b;
}

// ---- sync primitives ------------------------------------------------------
// Local mode: flags in the XCD's shared L2. sc0 store = write-through to L2;
// sc0 load = GLC semantics, bypass L1, read L2. Producers ALWAYS also publish
// an agent-scope copy on a separate (sc1-only, 256B-padded) line; consumers
// fall back to it (sticky) if the sc0 line doesn't advance -> no deadlock.

// one sc0 poll round over a 16-u32 line; returns 1 if min >= v
static __device__ __forceinline__ int poll16_l2(const unsigned* sig, int v) {
  i32x4 a, b, c, d;
  asm volatile(
      "global_load_dwordx4 %0, %4, off sc0\n\t"
      "global_load_dwordx4 %1, %5, off sc0\n\t"
      "global_load_dwordx4 %2, %6, off sc0\n\t"
      "global_load_dwordx4 %3, %7, off sc0\n\t"
      "s_waitcnt vmcnt(0)"
      : "=&v"(a), "=&v"(b), "=&v"(c), "=&v"(d)
      : "v"(sig), "v"(sig + 4), "v"(sig + 8), "v"(sig + 12)
      : "memory");
  int mn = a[0];
#pragma unroll
  for (int i = 1; i < 4; ++i) mn = a[i] < mn ? a[i] : mn;
#pragma unroll
  for (int i = 0; i < 4; ++i) {
    mn = b[i] < mn ? b[i] : mn;
    mn = c[i] < mn ? c[i] : mn;
    mn = d[i] < mn ? d[i] : mn;
  }
  return mn >= v;
}

// wait until all 16 producer counters >= v (L2 line first, agent line backup)
static __device__ __forceinline__ void wait16_dual(const unsigned* sigL,
                                                   const unsigned* sigF,
                                                   int v, bool local,
                                                   int* fb) {
  if (local && !*fb) {
    for (int tries = 0; tries < 20000; ++tries)     // ~2ms cap; real: <20
      if (poll16_l2(sigL, v)) return;
    *fb = 1;   // sticky: sc0 polling unproductive -> agent line from now on
  }
  for (;;) {
    unsigned mn = 0xffffffffu;
#pragma unroll
    for (int i = 0; i < 16; ++i) {
      unsigned x = __hip_atomic_load(&sigF[i], __ATOMIC_RELAXED,
                                     __HIP_MEMORY_SCOPE_AGENT);
      mn = x < mn ? x : mn;
    }
    if (mn >= (unsigned)v) break;
  }
  __builtin_amdgcn_fence(__ATOMIC_ACQUIRE, "agent");
}

// publish step v: sc0 copy (local mode) + agent copy (always; safety net and
// the only copy in fallback mode). Prior h-stores are drained by the
// preceding __syncthreads() vmcnt(0) before this runs.
static __device__ __forceinline__ void signal(unsigned* pL, unsigned* pF,
                                              int v, bool local) {
  if (local) {
    unsigned u = (unsigned)v;
    asm volatile("global_store_dword %0, %1, off sc0"
                 :: "v"(pL), "v"(u) : "memory");
  }
  __hip_atomic_store(pF, (unsigned)v, __ATOMIC_RELAXED,
                     __HIP_MEMORY_SCOPE_AGENT);
}

// h-state store: plain (write-through L1 -> own-XCD L2) when the group is
// verified co-located; agent-scope (LLC) otherwise.
static __device__ __forceinline__ void h_store(unsigned short* p,
                                               unsigned short v, bool local) {
  if (local) *p = v;
  else __hip_atomic_store(p, v, __ATOMIC_RELAXED, __HIP_MEMORY_SCOPE_AGENT);
}

// ---------------- f32 -> bf16 conversion (vectorized) ----------------------
__global__ void cvt_bf16(const float* __restrict__ src,
                         unsigned short* __restrict__ dst, int n4) {
  int i = blockIdx.x * blockDim.x + threadIdx.x;
  if (i < n4) {
    f32x4 v = ((const f32x4*)src)[i];
    s16x4 o;
    o[0] = (short)f2bf(v[0]); o[1] = (short)f2bf(v[1]);
    o[2] = (short)f2bf(v[2]); o[3] = (short)f2bf(v[3]);
    ((s16x4*)dst)[i] = o;
  }
}

// ---------------- big MFMA GEMM: C[M,N] = A[M,K]@W[N,K]^T + b1 (+b2) -------
template <bool BF16OUT>
__global__ __launch_bounds__(256)
void gemm_bf16(const unsigned short* __restrict__ A,
               const unsigned short* __restrict__ W,
               const float* __restrict__ b1, const float* __restrict__ b2,
               void* __restrict__ Cv, int Mx, int Nx, int Kx) {
  __shared__ __align__(16) unsigned short As[128 * 40];
  __shared__ __align__(16) unsigned short Bs[128 * 40];
  const int tid  = threadIdx.x;
  const int m0   = blockIdx.y * 128;
  const int n0   = blockIdx.x * 128;
  const int w    = tid >> 6, lane = tid & 63;
  const int quad = lane >> 4, l15 = lane & 15;
  const int wm = (w & 1) * 64, wn = (w >> 1) * 64;

  f32x4 acc[4][4] = {};

  for (int k0 = 0; k0 < Kx; k0 += 32) {
#pragma unroll
    for (int i = 0; i < 2; ++i) {
      int c = tid + i * 256;
      int row = c >> 2, kc = c & 3;
      *(i32x4*)&As[row * 40 + kc * 8] =
          *(const i32x4*)&A[(size_t)(m0 + row) * Kx + k0 + kc * 8];
      *(i32x4*)&Bs[row * 40 + kc * 8] =
          *(const i32x4*)&W[(size_t)(n0 + row) * Kx + k0 + kc * 8];
    }
    __syncthreads();
    bf16x8 af[4], bg[4];
#pragma unroll
    for (int im = 0; im < 4; ++im)
      af[im] = *(const bf16x8*)&As[(wm + im * 16 + l15) * 40 + quad * 8];
#pragma unroll
    for (int in = 0; in < 4; ++in)
      bg[in] = *(const bf16x8*)&Bs[(wn + in * 16 + l15) * 40 + quad * 8];
#pragma unroll
    for (int im = 0; im < 4; ++im)
#pragma unroll
      for (int in = 0; in < 4; ++in)
        acc[im][in] = __builtin_amdgcn_mfma_f32_16x16x32_bf16(
            af[im], bg[in], acc[im][in], 0, 0, 0);
    __syncthreads();
  }

#pragma unroll
  for (int in = 0; in < 4; ++in) {
    int n = n0 + wn + in * 16 + l15;
    float bv = b1 ? b1[n] : 0.f;
    if (b2) bv += b2[n];
#pragma unroll
    for (int im = 0; im < 4; ++im) {
      int mb = m0 + wm + im * 16 + quad * 4;   // C/D: row = quad*4+reg, col = l15
#pragma unroll
      for (int r = 0; r < 4; ++r) {
        float val = acc[im][in][r] + bv;
        size_t o = (size_t)(mb + r) * Nx + n;
        if (BF16OUT) ((unsigned short*)Cv)[o] = f2bf(val);
        else         ((float*)Cv)[o] = val;
      }
    }
  }
}

// ---------------- fused dual-layer persistent recurrence -------------------
// flags layout (u32):
//   [0..127]               xcdtab: published (XCC_ID+1) per active WG
//   128 + (g*3+k)*64       L-lines (sc0-only): k=0 sigA (L0->L0), k=1 sigB
//                          (L0->L1), k=2 sigC (L1->L1). 16 used + 48 pad so
//                          no two lines share a 128B L2 line.
//   896 + (g*3+k)*64       F-lines (agent-only), same k meaning.
// Producer p stores t+1 after finishing step t (no RMW; 16 independent
// stores land in parallel, consumer polls one 64B line).
__global__ __launch_bounds__(256, 1)
void rnn_fused(const unsigned short* __restrict__ Whh0,   // [H,H] bf16
               const unsigned short* __restrict__ Wih1,   // [H,H] bf16
               const unsigned short* __restrict__ Whh1,   // [H,H] bf16
               const unsigned short* __restrict__ pre0,   // [B,S,H] bf16
               const float* __restrict__ b_ih_1,
               const float* __restrict__ b_hh_1,
               unsigned short* __restrict__ h0seq,        // [B,S,H] bf16
               unsigned short* __restrict__ h1seq,        // [B,S,H] bf16
               unsigned int* __restrict__ flags)          // zeroed, 1664 u32
{
  const int bx  = blockIdx.x;
  const int res = bx & 7;
  if (res & 1) return;              // idle half of the grid
  const int g   = res >> 1;         // group 0..3 (16 batches each)
  const int r   = bx >> 3;          // rank within XCD slot, 0..31
  const int tid = threadIdx.x;
  const int w    = tid >> 6;        // wave = k-slice (256 wide)
  const int lane = tid & 63;
  const int quad = lane >> 4, l15 = lane & 15;
  const int n0   = (r & 15) * 64;   // 64 output cols per WG (both layers)

  unsigned* xcdtab = flags;
  unsigned* sigAL = flags + 128 + (g * 3 + 0) * 64;
  unsigned* sigBL = flags + 128 + (g * 3 + 1) * 64;
  unsigned* sigCL = flags + 128 + (g * 3 + 2) * 64;
  unsigned* sigAF = flags + 896 + (g * 3 + 0) * 64;
  unsigned* sigBF = flags + 896 + (g * 3 + 1) * 64;
  unsigned* sigCF = flags + 896 + (g * 3 + 2) * 64;

  __shared__ int s_local;
  __shared__ __align__(16) float q[4][4][16][20];  // [wave][ntile][col][4r pad20]

  // ---- setup: discover XCD, publish, verify group co-location (BOUNDED) ----
  if (tid == 0) {
    // HW_REG_XCC_ID = id 20, offset 0, size 4  (simm16 = (size-1)<<11 | id)
    unsigned tag =
        ((unsigned)__builtin_amdgcn_s_getreg((3 << 11) | 20) & 0xFu) + 1u;
    __hip_atomic_store(&xcdtab[g * 32 + r], tag, __ATOMIC_RELEASE,
                       __HIP_MEMORY_SCOPE_AGENT);
    unsigned long long t0 = __builtin_amdgcn_s_memrealtime();
    bool timeout = false;
    for (;;) {
      bool all = true;
      for (int i = 0; i < NACT; ++i)
        if (__hip_atomic_load(&xcdtab[i], __ATOMIC_RELAXED,
                              __HIP_MEMORY_SCOPE_AGENT) == 0u) {
          all = false; break;
        }
      if (all) break;
      if (__builtin_amdgcn_s_memrealtime() - t0 > 5000000ull) {
        timeout = true; break;
      }
      __builtin_amdgcn_s_sleep(8);
    }
    int verdict = 0;
    if (timeout) {
      __hip_atomic_store(&xcdtab[g * 32 + r], POISON_TAG, __ATOMIC_RELAXED,
                         __HIP_MEMORY_SCOPE_AGENT);
    } else {
      __builtin_amdgcn_fence(__ATOMIC_ACQUIRE, "agent");
      bool loc = true;
      int  cnt = 0;
      for (int i = 0; i < NACT; ++i) {
        unsigned v = __hip_atomic_load(&xcdtab[i], __ATOMIC_RELAXED,
                                       __HIP_MEMORY_SCOPE_AGENT);
        if ((i >> 5) == g) loc &= (v == tag);
        cnt += (v == tag) ? 1 : 0;
      }
      // cnt==32: exactly our 32 1-per-CU WGs on this XCD; also defeats a
      // bogus/constant getreg readout (all-same tag -> cnt=128 -> false).
      verdict = (loc && cnt == 32) ? 1 : 0;
    }
    s_local = verdict;
  }
  __syncthreads();
  const bool local = (s_local != 0);

  if (r < 16) {
    // ================= layer 0: 16 WGs/group, 64 cols =================
    i32x4 Wf[4][8];
    {
      const unsigned short* wp =
          Whh0 + (size_t)(n0 + l15) * H_ + w * 256 + quad * 8;
#pragma unroll
      for (int i = 0; i < 4; ++i)
#pragma unroll
        for (int kk = 0; kk < 8; ++kk)
          Wf[i][kk] = *(const i32x4*)(wp + (size_t)i * 16 * H_ + kk * 32);
    }
#pragma unroll
    for (int i = 0; i < 4; ++i)
#pragma unroll
      for (int kk = 0; kk < 8; ++kk)
        asm volatile("" : "+a"(Wf[i][kk]));   // pin in AGPRs (unified file)

    int fb = 0;
    for (int t = 0; t < S_; ++t) {
      float pv[4];   // pre0 prefetch: issue before the wait
      {
        const unsigned short* pp = pre0 + (size_t)(g * 16 + quad * 4) * SH_ +
                                   (size_t)t * H_ + n0 + w * 16 + l15;
#pragma unroll
        for (int u = 0; u < 4; ++u) pv[u] = bf2f(pp[(size_t)u * SH_]);
      }

      f32x4 acc[4] = {};
      if (t > 0) {
        if (tid == 0) wait16_dual(sigAL, sigAF, t, local, &fb);
        __syncthreads();
        const unsigned short* hp = h0seq + (size_t)(g * 16 + l15) * SH_ +
                                   (size_t)(t - 1) * H_ + w * 256 + quad * 8;
        bf16x8 Af[8];
#pragma unroll
        for (int kk = 0; kk < 8; ++kk) Af[kk] = *(const bf16x8*)(hp + kk * 32);
#pragma unroll
        for (int kk = 0; kk < 8; ++kk)
#pragma unroll
          for (int i = 0; i < 4; ++i)
            acc[i] = __builtin_amdgcn_mfma_f32_16x16x32_bf16(
                Af[kk], as_bf16x8(Wf[i][kk]), acc[i], 0, 0, 0);
      }

      // split-K reduce through LDS
#pragma unroll
      for (int i = 0; i < 4; ++i) *(f32x4*)&q[w][i][l15][quad * 4] = acc[i];
      __syncthreads();
      f32x4 s = {};
#pragma unroll
      for (int wp2 = 0; wp2 < 4; ++wp2) {
        f32x4 v = *(const f32x4*)&q[wp2][w][l15][quad * 4];
#pragma unroll
        for (int u = 0; u < 4; ++u) s[u] += v[u];
      }

#pragma unroll
      for (int u = 0; u < 4; ++u) {
        unsigned short hb = f2bf(tanh_fast(pv[u] + s[u]));
        size_t o = (size_t)(g * 16 + quad * 4 + u) * SH_ + (size_t)t * H_ +
                   n0 + w * 16 + l15;
        h_store(&h0seq[o], hb, local);
      }
      __syncthreads();   // vmcnt(0) drain of all waves' h stores; WAR on q
      if (tid == 0) {
        signal(&sigAL[r], &sigAF[r], t + 1, local);
        signal(&sigBL[r], &sigBF[r], t + 1, local);
      }
    }
  } else {
    // ================= layer 1: 16 WGs/group, 64 cols =================
    const int p1 = r - 16;
    i32x4 Wi[4][8], Wr[4][8];
    {
      const unsigned short* wpi =
          Wih1 + (size_t)(n0 + l15) * H_ + w * 256 + quad * 8;
      const unsigned short* wpr =
          Whh1 + (size_t)(n0 + l15) * H_ + w * 256 + quad * 8;
#pragma unroll
      for (int i = 0; i < 4; ++i)
#pragma unroll
        for (int kk = 0; kk < 8; ++kk) {
          Wi[i][kk] = *(const i32x4*)(wpi + (size_t)i * 16 * H_ + kk * 32);
          Wr[i][kk] = *(const i32x4*)(wpr + (size_t)i * 16 * H_ + kk * 32);
        }
    }
#pragma unroll
    for (int i = 0; i < 4; ++i)
#pragma unroll
      for (int kk = 0; kk < 8; ++kk) {
        asm volatile("" : "+a"(Wi[i][kk]));   // AGPR-pinned: no spill
        asm volatile("" : "+a"(Wr[i][kk]));
      }

    float bias;
    {
      int n = n0 + w * 16 + l15;
      bias = b_ih_1[n] + b_hh_1[n];
    }

    int fb = 0;
    for (int t = 0; t < S_; ++t) {
      f32x4 acc[4] = {};

      // --- input projection: needs h0_t (off the f1 chain; L0 runs ahead)
      if (tid == 0) wait16_dual(sigBL, sigBF, t + 1, local, &fb);
      __syncthreads();
      {
        const unsigned short* hp = h0seq + (size_t)(g * 16 + l15) * SH_ +
                                   (size_t)t * H_ + w * 256 + quad * 8;
        bf16x8 Af[8];
#pragma unroll
        for (int kk = 0; kk < 8; ++kk) Af[kk] = *(const bf16x8*)(hp + kk * 32);
#pragma unroll
        for (int kk = 0; kk < 8; ++kk)
#pragma unroll
          for (int i = 0; i < 4; ++i)
            acc[i] = __builtin_amdgcn_mfma_f32_16x16x32_bf16(
                Af[kk], as_bf16x8(Wi[i][kk]), acc[i], 0, 0, 0);
      }

      // --- recurrence: the serial chain (needs h1_{t-1})
      if (t > 0) {
        if (tid == 0) wait16_dual(sigCL, sigCF, t, local, &fb);
        __syncthreads();
        const unsigned short* hp = h1seq + (size_t)(g * 16 + l15) * SH_ +
                                   (size_t)(t - 1) * H_ + w * 256 + quad * 8;
        bf16x8 Af[8];
#pragma unroll
        for (int kk = 0; kk < 8; ++kk) Af[kk] = *(const bf16x8*)(hp + kk * 32);
#pragma unroll
        for (int kk = 0; kk < 8; ++kk)
#pragma unroll
          for (int i = 0; i < 4; ++i)
            acc[i] = __builtin_amdgcn_mfma_f32_16x16x32_bf16(
                Af[kk], as_bf16x8(Wr[i][kk]), acc[i], 0, 0, 0);
      }

      // --- split-K reduce + epilogue (all 4 waves; wave w owns ntile w)
#pragma unroll
      for (int i = 0; i < 4; ++i) *(f32x4*)&q[w][i][l15][quad * 4] = acc[i];
      __syncthreads();
      f32x4 s = {};
#pragma unroll
      for (int wp2 = 0; wp2 < 4; ++wp2) {
        f32x4 v = *(const f32x4*)&q[wp2][w][l15][quad * 4];
#pragma unroll
        for (int u = 0; u < 4; ++u) s[u] += v[u];
      }
#pragma unroll
      for (int u = 0; u < 4; ++u) {
        unsigned short hb = f2bf(tanh_fast(bias + s[u]));
        size_t o = (size_t)(g * 16 + quad * 4 + u) * SH_ + (size_t)t * H_ +
                   n0 + w * 16 + l15;
        h_store(&h1seq[o], hb, local);
      }
      __syncthreads();   // drain before the flag publish
      if (tid == 0) signal(&sigCL[p1], &sigCF[p1], t + 1, local);
    }
  }
}

// ---------------------------------------------------------------------------
extern "C" void kernel_launch(void* const* d_in, const int* in_sizes, int n_in,
                              void* d_out, int out_size, void* d_ws, size_t ws_size,
                              hipStream_t stream) {
  const float* x      = (const float*)d_in[0];
  const float* W_ih_0 = (const float*)d_in[1];
  const float* W_hh_0 = (const float*)d_in[2];
  const float* b_ih_0 = (const float*)d_in[3];
  const float* b_hh_0 = (const float*)d_in[4];
  const float* W_ih_1 = (const float*)d_in[5];
  const float* W_hh_1 = (const float*)d_in[6];
  const float* b_ih_1 = (const float*)d_in[7];
  const float* b_hh_1 = (const float*)d_in[8];
  const float* fc_w   = (const float*)d_in[9];
  const float* fc_b   = (const float*)d_in[10];
  float* out = (float*)d_out;

  char* ws = (char*)d_ws;
  size_t off = 0;
  auto alloc = [&](size_t bytes) { char* p = ws + off; off += (bytes + 255) & ~(size_t)255; return p; };
  unsigned short* xb    = (unsigned short*)alloc((size_t)M_ * I_ * 2);   // 16.8 MB
  unsigned short* wih0b = (unsigned short*)alloc((size_t)H_ * I_ * 2);
  unsigned short* whh0b = (unsigned short*)alloc((size_t)H_ * H_ * 2);
  unsigned short* wih1b = (unsigned short*)alloc((size_t)H_ * H_ * 2);
  unsigned short* whh1b = (unsigned short*)alloc((size_t)H_ * H_ * 2);
  unsigned short* fcwb  = (unsigned short*)alloc((size_t)O_ * H_ * 2);
  unsigned int*   flags = (unsigned int*)alloc(1664 * 4);                // 6.5 KB
  unsigned short* pre0b = (unsigned short*)alloc((size_t)M_ * H_ * 2);   // 67 MB
  unsigned short* h0seq = (unsigned short*)alloc((size_t)M_ * H_ * 2);   // 67 MB
  unsigned short* h1seq = (unsigned short*)alloc((size_t)M_ * H_ * 2);   // 67 MB

  hipMemsetAsync(flags, 0, 1664 * 4, stream);

  auto cvt = [&](const float* s, unsigned short* d, int n) {
    int n4 = n / 4;
    cvt_bf16<<<(n4 + 255) / 256, 256, 0, stream>>>(s, d, n4);
  };
  cvt(x,      xb,    M_ * I_);
  cvt(W_ih_0, wih0b, H_ * I_);
  cvt(W_hh_0, whh0b, H_ * H_);
  cvt(W_ih_1, wih1b, H_ * H_);
  cvt(W_hh_1, whh1b, H_ * H_);
  cvt(fc_w,   fcwb,  O_ * H_);

  // pre0 = x @ W_ih0^T + b_ih0 + b_hh0  (bf16 out)
  gemm_bf16<true><<<dim3(H_ / 128, M_ / 128), 256, 0, stream>>>(
      xb, wih0b, b_ih_0, b_hh_0, pre0b, M_, H_, I_);

  // fused dual-layer recurrence; L2-scope flags + h-data when verified local
  rnn_fused<<<256, 256, 0, stream>>>(whh0b, wih1b, whh1b, pre0b,
                                     b_ih_1, b_hh_1, h0seq, h1seq, flags);

  // FC head
  gemm_bf16<false><<<dim3(O_ / 128, M_ / 128), 256, 0, stream>>>(
      h1seq, fcwb, fc_b, nullptr, out, M_, O_, H_);
}

// Round 5
// 3987.244 us; speedup vs baseline: 1.7567x; 1.7567x over previous
//
#include <hip/hip_runtime.h>
#include <hip/hip_bf16.h>

// ---------------------------------------------------------------------------
// 2-layer tanh RNN + FC head on MI355X (gfx950).
// Round 8: LDS-resident recurrent weights.
//   Lesson r6/r7: pinning 128-256 weight VGPRs/lane never sticks (compiler
//   spills; per-step scratch reloads on the serial chain caused both
//   regressions), and sc0 cross-CU polling does NOT work (r7: one sticky
//   2.2ms timeout per consumer == the whole 4845->7004 delta).
//   Fix: weights live in LDS (128KB slice, fragment-ordered, conflict-free
//   ds_read_b128); layer-1 streams Wih1 from L2 (off the serial chain).
//   Sync: EXACTLY the validated round-6 protocol (agent-scope flags with
//   16 parallel per-producer stores on padded lines; plain h-stores under
//   the verified XCD-local verdict; bounded rendezvous + poison fallback).
//   B=64 S=512 I=256 H=1024 O=256
//   grid 256: bx%8 even -> group (bx%8)/2, rank bx/8 (0..31):
//     rank<16 : layer-0 WG, 64 cols;  rank>=16: layer-1 WG, 64 cols
//   bx%8 odd -> exit. 151KB LDS -> 1 WG/CU; idle WGs exit instantly so the
//   128 active WGs always find CUs (no placement deadlock).
// ---------------------------------------------------------------------------

typedef __attribute__((ext_vector_type(4))) float f32x4;
typedef __attribute__((ext_vector_type(8))) short bf16x8;
typedef __attribute__((ext_vector_type(4))) int   i32x4;
typedef __attribute__((ext_vector_type(4))) short s16x4;

#define B_  64
#define S_  512
#define I_  256
#define H_  1024
#define O_  256
#define M_  (B_ * S_)     // 32768
#define SH_ (S_ * H_)     // 524288 (row stride of h-seq / pre in elements)
#define NACT 128          // active WGs (4 groups x 32)
#define POISON_TAG 0xFFu  // nonzero, != any real tag (tags are 1..16)

static __device__ __forceinline__ unsigned short f2bf(float f) {
  union { float f; unsigned u; } v; v.f = f;
  unsigned r = v.u + 0x7fffu + ((v.u >> 16) & 1u);   // RNE
  return (unsigned short)(r >> 16);
}
static __device__ __forceinline__ float bf2f(unsigned short b) {
  union { unsigned u; float f; } v; v.u = ((unsigned)b) << 16;
  return v.f;
}
static __device__ __forceinline__ float tanh_fast(float x) {
  float e = __expf(2.f * x);
  return 1.f - 2.f / (e + 1.f);
}
static __device__ __forceinline__ bf16x8 as_bf16x8(i32x4 v) {
  union { i32x4 i; bf16x8 b; } u; u.i = v; return u.b;
}

// ---- sync primitives (flags ALWAYS agent scope — validated r2/r4/r6) ------

// wait until all 16 producer counters >= v
static __device__ __forceinline__ void wait16(const unsigned* sig, int v) {
  for (;;) {
    unsigned mn = 0xffffffffu;
#pragma unroll
    for (int i = 0; i < 16; ++i) {
      unsigned x = __hip_atomic_load(&sig[i], __ATOMIC_RELAXED,
                                     __HIP_MEMORY_SCOPE_AGENT);
      mn = x < mn ? x : mn;
    }
    if (mn >= (unsigned)v) break;
    __builtin_amdgcn_s_sleep(2);
  }
  __builtin_amdgcn_fence(__ATOMIC_ACQUIRE, "agent");
}

static __device__ __forceinline__ void sig_store(unsigned* p, int v) {
  // prior h-stores drained by the preceding barrier's vmcnt(0)
  __hip_atomic_store(p, (unsigned)v, __ATOMIC_RELAXED,
                     __HIP_MEMORY_SCOPE_AGENT);
}

// h-state store: plain (write-through to own-XCD L2) when the group is
// verified co-located (validated r6: passed, FETCH 794->141MB); agent-scope
// (LLC) otherwise. Consumer loads are plain and t-fresh (never L1-cached).
static __device__ __forceinline__ void h_store(unsigned short* p,
                                               unsigned short v, bool local) {
  if (local) *p = v;
  else __hip_atomic_store(p, v, __ATOMIC_RELAXED, __HIP_MEMORY_SCOPE_AGENT);
}

// ---------------- f32 -> bf16 conversion (vectorized) ----------------------
__global__ void cvt_bf16(const float* __restrict__ src,
                         unsigned short* __restrict__ dst, int n4) {
  int i = blockIdx.x * blockDim.x + threadIdx.x;
  if (i < n4) {
    f32x4 v = ((const f32x4*)src)[i];
    s16x4 o;
    o[0] = (short)f2bf(v[0]); o[1] = (short)f2bf(v[1]);
    o[2] = (short)f2bf(v[2]); o[3] = (short)f2bf(v[3]);
    ((s16x4*)dst)[i] = o;
  }
}

// ---------------- big MFMA GEMM: C[M,N] = A[M,K]@W[N,K]^T + b1 (+b2) -------
template <bool BF16OUT>
__global__ __launch_bounds__(256)
void gemm_bf16(const unsigned short* __restrict__ A,
               const unsigned short* __restrict__ W,
               const float* __restrict__ b1, const float* __restrict__ b2,
               void* __restrict__ Cv, int Mx, int Nx, int Kx) {
  __shared__ __align__(16) unsigned short As[128 * 40];
  __shared__ __align__(16) unsigned short Bs[128 * 40];
  const int tid  = threadIdx.x;
  const int m0   = blockIdx.y * 128;
  const int n0   = blockIdx.x * 128;
  const int w    = tid >> 6, lane = tid & 63;
  const int quad = lane >> 4, l15 = lane & 15;
  const int wm = (w & 1) * 64, wn = (w >> 1) * 64;

  f32x4 acc[4][4] = {};

  for (int k0 = 0; k0 < Kx; k0 += 32) {
#pragma unroll
    for (int i = 0; i < 2; ++i) {
      int c = tid + i * 256;
      int row = c >> 2, kc = c & 3;
      *(i32x4*)&As[row * 40 + kc * 8] =
          *(const i32x4*)&A[(size_t)(m0 + row) * Kx + k0 + kc * 8];
      *(i32x4*)&Bs[row * 40 + kc * 8] =
          *(const i32x4*)&W[(size_t)(n0 + row) * Kx + k0 + kc * 8];
    }
    __syncthreads();
    bf16x8 af[4], bg[4];
#pragma unroll
    for (int im = 0; im < 4; ++im)
      af[im] = *(const bf16x8*)&As[(wm + im * 16 + l15) * 40 + quad * 8];
#pragma unroll
    for (int in = 0; in < 4; ++in)
      bg[in] = *(const bf16x8*)&Bs[(wn + in * 16 + l15) * 40 + quad * 8];
#pragma unroll
    for (int im = 0; im < 4; ++im)
#pragma unroll
      for (int in = 0; in < 4; ++in)
        acc[im][in] = __builtin_amdgcn_mfma_f32_16x16x32_bf16(
            af[im], bg[in], acc[im][in], 0, 0, 0);
    __syncthreads();
  }

#pragma unroll
  for (int in = 0; in < 4; ++in) {
    int n = n0 + wn + in * 16 + l15;
    float bv = b1 ? b1[n] : 0.f;
    if (b2) bv += b2[n];
#pragma unroll
    for (int im = 0; im < 4; ++im) {
      int mb = m0 + wm + im * 16 + quad * 4;   // C/D: row = quad*4+reg, col = l15
#pragma unroll
      for (int r = 0; r < 4; ++r) {
        float val = acc[im][in][r] + bv;
        size_t o = (size_t)(mb + r) * Nx + n;
        if (BF16OUT) ((unsigned short*)Cv)[o] = f2bf(val);
        else         ((float*)Cv)[o] = val;
      }
    }
  }
}

// ---------------- fused dual-layer persistent recurrence -------------------
// flags layout (u32):
//   [0..127]             xcdtab: published (XCC_ID+1) per active WG
//   128 + (g*3+k)*64     sig lines, 16 used + 48 pad (no 128B-line sharing):
//                        k=0 sigA (L0->L0), k=1 sigB (L0->L1), k=2 sigC
//                        (L1->L1). Producer p stores t+1 after step t.
__global__ __launch_bounds__(256, 1)
void rnn_fused(const unsigned short* __restrict__ Whh0,   // [H,H] bf16
               const unsigned short* __restrict__ Wih1,   // [H,H] bf16
               const unsigned short* __restrict__ Whh1,   // [H,H] bf16
               const unsigned short* __restrict__ pre0,   // [B,S,H] bf16
               const float* __restrict__ b_ih_1,
               const float* __restrict__ b_hh_1,
               unsigned short* __restrict__ h0seq,        // [B,S,H] bf16
               unsigned short* __restrict__ h1seq,        // [B,S,H] bf16
               unsigned int* __restrict__ flags)          // zeroed, 1024 u32
{
  const int bx  = blockIdx.x;
  const int res = bx & 7;
  if (res & 1) return;              // idle half of the grid
  const int g   = res >> 1;         // group 0..3 (16 batches each)
  const int r   = bx >> 3;          // rank within XCD slot, 0..31
  const int tid = threadIdx.x;
  const int w    = tid >> 6;        // wave = k-slice (256 wide)
  const int lane = tid & 63;
  const int quad = lane >> 4, l15 = lane & 15;
  const int n0   = (r & 15) * 64;   // 64 output cols per WG (both layers)

  unsigned* xcdtab = flags;
  unsigned* sigA = flags + 128 + (g * 3 + 0) * 64;
  unsigned* sigB = flags + 128 + (g * 3 + 1) * 64;
  unsigned* sigC = flags + 128 + (g * 3 + 2) * 64;

  // 128KB fragment-ordered weight store + 20KB reduce buffer = 151.5KB LDS.
  // Fragment layout: frag f=(w*32+i*8+kk) at Wlds[(f*64+lane)*8 .. +8] ->
  // every ds_read_b128 is lane-stride-16B => conflict-free (2-way is free).
  __shared__ __align__(16) unsigned short Wlds[65536];
  __shared__ __align__(16) float q[4][4][16][20];  // [wave][ntile][col][4r pad20]
  __shared__ int s_local;

  // ---- setup: discover XCD, publish, verify co-location (BOUNDED, r6) ----
  if (tid == 0) {
    // HW_REG_XCC_ID = id 20, offset 0, size 4  (simm16 = (size-1)<<11 | id)
    unsigned tag =
        ((unsigned)__builtin_amdgcn_s_getreg((3 << 11) | 20) & 0xFu) + 1u;
    __hip_atomic_store(&xcdtab[g * 32 + r], tag, __ATOMIC_RELEASE,
                       __HIP_MEMORY_SCOPE_AGENT);
    unsigned long long t0 = __builtin_amdgcn_s_memrealtime();
    bool timeout = false;
    for (;;) {
      bool all = true;
      for (int i = 0; i < NACT; ++i)
        if (__hip_atomic_load(&xcdtab[i], __ATOMIC_RELAXED,
                              __HIP_MEMORY_SCOPE_AGENT) == 0u) {
          all = false; break;
        }
      if (all) break;
      if (__builtin_amdgcn_s_memrealtime() - t0 > 5000000ull) {
        timeout = true; break;
      }
      __builtin_amdgcn_s_sleep(8);
    }
    int verdict = 0;
    if (timeout) {
      __hip_atomic_store(&xcdtab[g * 32 + r], POISON_TAG, __ATOMIC_RELAXED,
                         __HIP_MEMORY_SCOPE_AGENT);
    } else {
      __builtin_amdgcn_fence(__ATOMIC_ACQUIRE, "agent");
      bool loc = true;
      int  cnt = 0;
      for (int i = 0; i < NACT; ++i) {
        unsigned v = __hip_atomic_load(&xcdtab[i], __ATOMIC_RELAXED,
                                       __HIP_MEMORY_SCOPE_AGENT);
        if ((i >> 5) == g) loc &= (v == tag);
        cnt += (v == tag) ? 1 : 0;
      }
      verdict = (loc && cnt == 32) ? 1 : 0;
    }
    s_local = verdict;
  }

  // per-lane LDS fragment base (w's 32 frags start at frag w*32)
  unsigned short* Wl = &Wlds[(w * 32 * 64 + lane) * 8];

  if (r < 16) {
    // ================= layer 0: 16 WGs/group, 64 cols =================
    // stage Whh0 slice into LDS, fragment-ordered (one-time)
    {
      const unsigned short* wp =
          Whh0 + (size_t)(n0 + l15) * H_ + w * 256 + quad * 8;
#pragma unroll
      for (int i = 0; i < 4; ++i)
#pragma unroll
        for (int kk = 0; kk < 8; ++kk)
          *(i32x4*)&Wl[(i * 8 + kk) * 512] =
              *(const i32x4*)(wp + (size_t)i * 16 * H_ + kk * 32);
    }
    __syncthreads();                       // Wlds ready; s_local visible
    const bool local = (s_local != 0);

    for (int t = 0; t < S_; ++t) {
      float pv[4];   // pre0 prefetch: issue before the wait
      {
        const unsigned short* pp = pre0 + (size_t)(g * 16 + quad * 4) * SH_ +
                                   (size_t)t * H_ + n0 + w * 16 + l15;
#pragma unroll
        for (int u = 0; u < 4; ++u) pv[u] = bf2f(pp[(size_t)u * SH_]);
      }

      f32x4 acc[4] = {};
      if (t > 0) {
        if (tid == 0) wait16(sigA, t);
        __syncthreads();
        const unsigned short* hp = h0seq + (size_t)(g * 16 + l15) * SH_ +
                                   (size_t)(t - 1) * H_ + w * 256 + quad * 8;
        bf16x8 Af[8];
#pragma unroll
        for (int kk = 0; kk < 8; ++kk) Af[kk] = *(const bf16x8*)(hp + kk * 32);
#pragma unroll
        for (int kk = 0; kk < 8; ++kk)
#pragma unroll
          for (int i = 0; i < 4; ++i)
            acc[i] = __builtin_amdgcn_mfma_f32_16x16x32_bf16(
                Af[kk], *(const bf16x8*)&Wl[(i * 8 + kk) * 512],
                acc[i], 0, 0, 0);
      }

      // split-K reduce through LDS
#pragma unroll
      for (int i = 0; i < 4; ++i) *(f32x4*)&q[w][i][l15][quad * 4] = acc[i];
      __syncthreads();
      f32x4 s = {};
#pragma unroll
      for (int wp2 = 0; wp2 < 4; ++wp2) {
        f32x4 v = *(const f32x4*)&q[wp2][w][l15][quad * 4];
#pragma unroll
        for (int u = 0; u < 4; ++u) s[u] += v[u];
      }

#pragma unroll
      for (int u = 0; u < 4; ++u) {
        unsigned short hb = f2bf(tanh_fast(pv[u] + s[u]));
        size_t o = (size_t)(g * 16 + quad * 4 + u) * SH_ + (size_t)t * H_ +
                   n0 + w * 16 + l15;
        h_store(&h0seq[o], hb, local);
      }
      __syncthreads();   // vmcnt(0) drain of all waves' h stores; WAR on q
      if (tid == 0) {
        sig_store(&sigA[r], t + 1);
        sig_store(&sigB[r], t + 1);
      }
    }
  } else {
    // ================= layer 1: 16 WGs/group, 64 cols =================
    const int p1 = r - 16;
    // stage Whh1 (recurrent, chain-critical) into LDS; Wih1 streams from L2
    {
      const unsigned short* wp =
          Whh1 + (size_t)(n0 + l15) * H_ + w * 256 + quad * 8;
#pragma unroll
      for (int i = 0; i < 4; ++i)
#pragma unroll
        for (int kk = 0; kk < 8; ++kk)
          *(i32x4*)&Wl[(i * 8 + kk) * 512] =
              *(const i32x4*)(wp + (size_t)i * 16 * H_ + kk * 32);
    }
    __syncthreads();
    const bool local = (s_local != 0);

    const unsigned short* wpi =
        Wih1 + (size_t)(n0 + l15) * H_ + w * 256 + quad * 8;

    float bias;
    {
      int n = n0 + w * 16 + l15;
      bias = b_ih_1[n] + b_hh_1[n];
    }

    for (int t = 0; t < S_; ++t) {
      f32x4 acc[4] = {};

      // --- input projection: needs h0_t only (L0 runs ahead; off the
      //     serial chain). Wi streamed from L2, 2-deep 8-frag pipeline.
      if (tid == 0) wait16(sigB, t + 1);
      __syncthreads();
      {
        const unsigned short* hp = h0seq + (size_t)(g * 16 + l15) * SH_ +
                                   (size_t)t * H_ + w * 256 + quad * 8;
        bf16x8 Af[8];
#pragma unroll
        for (int kk = 0; kk < 8; ++kk) Af[kk] = *(const bf16x8*)(hp + kk * 32);
        i32x4 wa[8], wb[8];
#pragma unroll
        for (int kk = 0; kk < 8; ++kk)
          wa[kk] = *(const i32x4*)(wpi + (size_t)0 * 16 * H_ + kk * 32);
#pragma unroll
        for (int kk = 0; kk < 8; ++kk)
          wb[kk] = *(const i32x4*)(wpi + (size_t)1 * 16 * H_ + kk * 32);
#pragma unroll
        for (int kk = 0; kk < 8; ++kk)
          acc[0] = __builtin_amdgcn_mfma_f32_16x16x32_bf16(
              Af[kk], as_bf16x8(wa[kk]), acc[0], 0, 0, 0);
#pragma unroll
        for (int kk = 0; kk < 8; ++kk)
          wa[kk] = *(const i32x4*)(wpi + (size_t)2 * 16 * H_ + kk * 32);
#pragma unroll
        for (int kk = 0; kk < 8; ++kk)
          acc[1] = __builtin_amdgcn_mfma_f32_16x16x32_bf16(
              Af[kk], as_bf16x8(wb[kk]), acc[1], 0, 0, 0);
#pragma unroll
        for (int kk = 0; kk < 8; ++kk)
          wb[kk] = *(const i32x4*)(wpi + (size_t)3 * 16 * H_ + kk * 32);
#pragma unroll
        for (int kk = 0; kk < 8; ++kk)
          acc[2] = __builtin_amdgcn_mfma_f32_16x16x32_bf16(
              Af[kk], as_bf16x8(wa[kk]), acc[2], 0, 0, 0);
#pragma unroll
        for (int kk = 0; kk < 8; ++kk)
          acc[3] = __builtin_amdgcn_mfma_f32_16x16x32_bf16(
              Af[kk], as_bf16x8(wb[kk]), acc[3], 0, 0, 0);
      }

      // --- recurrence: the serial chain (needs h1_{t-1}); Wr from LDS
      if (t > 0) {
        if (tid == 0) wait16(sigC, t);
        __syncthreads();
        const unsigned short* hp = h1seq + (size_t)(g * 16 + l15) * SH_ +
                                   (size_t)(t - 1) * H_ + w * 256 + quad * 8;
        bf16x8 Af[8];
#pragma unroll
        for (int kk = 0; kk < 8; ++kk) Af[kk] = *(const bf16x8*)(hp + kk * 32);
#pragma unroll
        for (int kk = 0; kk < 8; ++kk)
#pragma unroll
          for (int i = 0; i < 4; ++i)
            acc[i] = __builtin_amdgcn_mfma_f32_16x16x32_bf16(
                Af[kk], *(const bf16x8*)&Wl[(i * 8 + kk) * 512],
                acc[i], 0, 0, 0);
      }

      // --- split-K reduce + epilogue (all 4 waves; wave w owns ntile w)
#pragma unroll
      for (int i = 0; i < 4; ++i) *(f32x4*)&q[w][i][l15][quad * 4] = acc[i];
      __syncthreads();
      f32x4 s = {};
#pragma unroll
      for (int wp2 = 0; wp2 < 4; ++wp2) {
        f32x4 v = *(const f32x4*)&q[wp2][w][l15][quad * 4];
#pragma unroll
        for (int u = 0; u < 4; ++u) s[u] += v[u];
      }
#pragma unroll
      for (int u = 0; u < 4; ++u) {
        unsigned short hb = f2bf(tanh_fast(bias + s[u]));
        size_t o = (size_t)(g * 16 + quad * 4 + u) * SH_ + (size_t)t * H_ +
                   n0 + w * 16 + l15;
        h_store(&h1seq[o], hb, local);
      }
      __syncthreads();   // drain before the flag publish
      if (tid == 0) sig_store(&sigC[p1], t + 1);
    }
  }
}

// ---------------------------------------------------------------------------
extern "C" void kernel_launch(void* const* d_in, const int* in_sizes, int n_in,
                              void* d_out, int out_size, void* d_ws, size_t ws_size,
                              hipStream_t stream) {
  const float* x      = (const float*)d_in[0];
  const float* W_ih_0 = (const float*)d_in[1];
  const float* W_hh_0 = (const float*)d_in[2];
  const float* b_ih_0 = (const float*)d_in[3];
  const float* b_hh_0 = (const float*)d_in[4];
  const float* W_ih_1 = (const float*)d_in[5];
  const float* W_hh_1 = (const float*)d_in[6];
  const float* b_ih_1 = (const float*)d_in[7];
  const float* b_hh_1 = (const float*)d_in[8];
  const float* fc_w   = (const float*)d_in[9];
  const float* fc_b   = (const float*)d_in[10];
  float* out = (float*)d_out;

  char* ws = (char*)d_ws;
  size_t off = 0;
  auto alloc = [&](size_t bytes) { char* p = ws + off; off += (bytes + 255) & ~(size_t)255; return p; };
  unsigned short* xb    = (unsigned short*)alloc((size_t)M_ * I_ * 2);   // 16.8 MB
  unsigned short* wih0b = (unsigned short*)alloc((size_t)H_ * I_ * 2);
  unsigned short* whh0b = (unsigned short*)alloc((size_t)H_ * H_ * 2);
  unsigned short* wih1b = (unsigned short*)alloc((size_t)H_ * H_ * 2);
  unsigned short* whh1b = (unsigned short*)alloc((size_t)H_ * H_ * 2);
  unsigned short* fcwb  = (unsigned short*)alloc((size_t)O_ * H_ * 2);
  unsigned int*   flags = (unsigned int*)alloc(1024 * 4);                // 4 KB
  unsigned short* pre0b = (unsigned short*)alloc((size_t)M_ * H_ * 2);   // 67 MB
  unsigned short* h0seq = (unsigned short*)alloc((size_t)M_ * H_ * 2);   // 67 MB
  unsigned short* h1seq = (unsigned short*)alloc((size_t)M_ * H_ * 2);   // 67 MB

  hipMemsetAsync(flags, 0, 1024 * 4, stream);

  auto cvt = [&](const float* s, unsigned short* d, int n) {
    int n4 = n / 4;
    cvt_bf16<<<(n4 + 255) / 256, 256, 0, stream>>>(s, d, n4);
  };
  cvt(x,      xb,    M_ * I_);
  cvt(W_ih_0, wih0b, H_ * I_);
  cvt(W_hh_0, whh0b, H_ * H_);
  cvt(W_ih_1, wih1b, H_ * H_);
  cvt(W_hh_1, whh1b, H_ * H_);
  cvt(fc_w,   fcwb,  O_ * H_);

  // pre0 = x @ W_ih0^T + b_ih0 + b_hh0  (bf16 out)
  gemm_bf16<true><<<dim3(H_ / 128, M_ / 128), 256, 0, stream>>>(
      xb, wih0b, b_ih_0, b_hh_0, pre0b, M_, H_, I_);

  // fused dual-layer recurrence (LDS-resident weights)
  rnn_fused<<<256, 256, 0, stream>>>(whh0b, wih1b, whh1b, pre0b,
                                     b_ih_1, b_hh_1, h0seq, h1seq, flags);

  // FC head
  gemm_bf16<false><<<dim3(O_ / 128, M_ / 128), 256, 0, stream>>>(
      h1seq, fcwb, fc_b, nullptr, out, M_, O_, H_);
}